// Round 5
// baseline (390.454 us; speedup 1.0000x reference)
//
#include <hip/hip_runtime.h>

// ---------------------------------------------------------------------------
// 3-layer GCN (DGL GraphConv, norm='both') on N=100k nodes, E=800k edges.
// Round 5:
//  - CSR replaced by fixed-capacity buckets (CAP=16) + exact spill list,
//    built in ONE fused pass (also computes both degree histograms).
//    Record = float4 {src_bits, w0, w1, w2}: one 16B random write per edge.
//  - invo folded into gather epilogue; hidden state stored bf16 -> GEMM A
//    loads fragments directly from global (no LDS, no barriers).
//  - W pre-packed to MFMA fragment order in global (pack_w kernels).
// Per layer: y = bf16(hb @ W) ; hb' = bf16(relu(gather(y)*invi + b) * invo)
// ---------------------------------------------------------------------------

typedef short s16x8 __attribute__((ext_vector_type(8)));
typedef float f32x4 __attribute__((ext_vector_type(4)));

static constexpr int CAP = 16;   // bucket slots per node

__device__ __forceinline__ unsigned short f2bf(float f) {
    unsigned int u = __float_as_uint(f);
    u += 0x7FFFu + ((u >> 16) & 1u);   // round-to-nearest-even
    return (unsigned short)(u >> 16);
}
__device__ __forceinline__ float bf2f(unsigned short v) {
    return __uint_as_float((unsigned int)v << 16);
}

// ---- fused bucket fill + degree histograms (one pass over edges) ----
__global__ __launch_bounds__(256)
void fill_bucket(const int* __restrict__ src, const int* __restrict__ dst,
                 const float* __restrict__ w, int E,
                 int* __restrict__ dego, int* __restrict__ cursor,
                 float4* __restrict__ swb,
                 int* __restrict__ spill_cnt, int2* __restrict__ spill) {
    int e = blockIdx.x * blockDim.x + threadIdx.x;
    if (e >= E) return;
    int s = src[e];
    int d = dst[e];
    atomicAdd(&dego[s], 1);
    int pos = atomicAdd(&cursor[d], 1);
    if (pos < CAP) {
        swb[(size_t)d * CAP + pos] =
            make_float4(__int_as_float(s), w[e], w[E + e], w[2 * (size_t)E + e]);
    } else {
        int sp = atomicAdd(spill_cnt, 1);
        spill[sp] = make_int2(d, e);
    }
}

__global__ void invsqrt_kernel(const int* __restrict__ dego, const int* __restrict__ degi,
                               float* __restrict__ invo, float* __restrict__ invi, int N) {
    int i = blockIdx.x * blockDim.x + threadIdx.x;
    if (i < N) {
        int a = dego[i]; if (a < 1) a = 1;
        int b = degi[i]; if (b < 1) b = 1;
        invo[i] = 1.0f / sqrtf((float)a);
        invi[i] = 1.0f / sqrtf((float)b);
    }
}

// ---- pre-pack W[128][dact] (f32) into MFMA fragment order (bf16), pad to PC
// Fragment mapping (same for A and B, cancels HW k-order):
//   k = kk*32 + (lane>>4)*8 + j ; col = ct*16 + (lane&15)
__global__ void pack_w(const float* __restrict__ W, int dact, int PC,
                       unsigned short* __restrict__ Wp) {
    int idx = blockIdx.x * blockDim.x + threadIdx.x;
    if (idx >= 128 * PC) return;
    int k = idx / PC, col = idx % PC;
    float v = (col < dact) ? W[(size_t)k * dact + col] : 0.0f;
    int CT = PC / 16;
    int kk = k >> 5, kr = k & 31;
    int lane = ((kr >> 3) << 4) | (col & 15);
    int ct = col >> 4, j = kr & 7;
    Wp[(((size_t)(kk * CT) + ct) * 64 + lane) * 8 + j] = f2bf(v);
}

// ---- layer-0 input prescale: xb = bf16(x * invo[row]) ----
__global__ __launch_bounds__(256)
void prescale(const float* __restrict__ x, const float* __restrict__ invo,
              unsigned short* __restrict__ xb, int N) {
    int gid = blockIdx.x * blockDim.x + threadIdx.x;   // over N*32 float4s
    if (gid >= N * 32) return;
    int row = gid >> 5;
    float s = invo[row];
    float4 v = *(const float4*)&x[(size_t)gid * 4];
    ushort4 o;
    o.x = f2bf(v.x * s); o.y = f2bf(v.y * s);
    o.z = f2bf(v.z * s); o.w = f2bf(v.w * s);
    *(ushort4*)&xb[(size_t)gid * 4] = o;
}

// ---------------------------------------------------------------------------
// LDS-free MFMA GEMM: y[N][PC](bf16) = bf16( h[N][128](bf16) @ Wp )
// Block = 4 waves = 64 rows; wave computes 16 rows x PC cols; K=128 in 4 steps.
// A fragments loaded directly from global (16B/lane); B from pre-packed Wp
// (contiguous 16B/lane, L2-hot broadcast across blocks).
// C/D layout: col = ct*16 + (lane&15), row = (lane>>4)*4 + i.
// ---------------------------------------------------------------------------
template<int PC>
__global__ __launch_bounds__(256)
void gemm_direct(const unsigned short* __restrict__ h,
                 const unsigned short* __restrict__ Wp,
                 unsigned short* __restrict__ y, int N) {
    constexpr int CT = PC / 16;
    const int lane = threadIdx.x & 63;
    const int wid  = threadIdx.x >> 6;
    const int row0 = blockIdx.x * 64 + wid * 16;
    const int kgrp = lane >> 4;
    const int c    = lane & 15;

    int ar = row0 + c;
    if (ar > N - 1) ar = N - 1;          // clamp (partial last block)
    const unsigned short* hrow = &h[(size_t)ar * 128 + kgrp * 8];

    f32x4 acc[CT];
    #pragma unroll
    for (int ct = 0; ct < CT; ++ct) acc[ct] = {0.f, 0.f, 0.f, 0.f};

    #pragma unroll
    for (int kk = 0; kk < 4; ++kk) {
        s16x8 af = *(const s16x8*)&hrow[kk * 32];
        #pragma unroll
        for (int ct = 0; ct < CT; ++ct) {
            s16x8 bf = *(const s16x8*)&Wp[((size_t)(kk * CT + ct) * 64 + lane) * 8];
            acc[ct] = __builtin_amdgcn_mfma_f32_16x16x32_bf16(af, bf, acc[ct], 0, 0, 0);
        }
    }

    #pragma unroll
    for (int ct = 0; ct < CT; ++ct) {
        #pragma unroll
        for (int i = 0; i < 4; ++i) {
            int row = row0 + kgrp * 4 + i;
            if (row < N) y[(size_t)row * PC + ct * 16 + c] = f2bf(acc[ct][i]);
        }
    }
}

// ---------------------------------------------------------------------------
// Bucket gather + fused finalize.
// WSEL picks the weight component (0->w0, 1->w1, 2->w2).
// Non-final: out = bf16( relu(acc*invi + b) * invo )  (pitch 128, bf16)
// Final:     out = acc*invi + b, f32, pitch 47, cols < 47 only.
// ---------------------------------------------------------------------------
template<int D, int WSEL, bool FINAL>
__global__ __launch_bounds__(256)
void gather_b(const unsigned short* __restrict__ yb, const float4* __restrict__ swb,
              const int* __restrict__ degi, const int* __restrict__ spill_cnt,
              const int2* __restrict__ spill, const int* __restrict__ src,
              const float* __restrict__ wl, const float* __restrict__ invi,
              const float* __restrict__ invo, const float* __restrict__ b,
              void* __restrict__ outp, int N) {
    constexpr int TPN = D / 4;          // threads per node
    constexpr int NPB = 256 / TPN;      // nodes per block
    const int n    = blockIdx.x * NPB + threadIdx.x / TPN;
    const int lane = threadIdx.x % TPN;
    if (n >= N) return;

    const ushort4* yv = (const ushort4*)yb;
    const float4* rec = swb + (size_t)n * CAP;
    const int dg  = degi[n];
    const int cnt = dg < CAP ? dg : CAP;

    float a0 = 0.f, a1 = 0.f, a2 = 0.f, a3 = 0.f;
    int p = 0;
    for (; p + 2 <= cnt; p += 2) {
        float4 m0 = rec[p];
        float4 m1 = rec[p + 1];
        int s0 = __float_as_int(m0.x);
        int s1 = __float_as_int(m1.x);
        float w0 = (WSEL == 0) ? m0.y : (WSEL == 1) ? m0.z : m0.w;
        float w1 = (WSEL == 0) ? m1.y : (WSEL == 1) ? m1.z : m1.w;
        ushort4 v0 = yv[(size_t)s0 * TPN + lane];
        ushort4 v1 = yv[(size_t)s1 * TPN + lane];
        a0 = fmaf(bf2f(v0.x), w0, a0);
        a1 = fmaf(bf2f(v0.y), w0, a1);
        a2 = fmaf(bf2f(v0.z), w0, a2);
        a3 = fmaf(bf2f(v0.w), w0, a3);
        a0 = fmaf(bf2f(v1.x), w1, a0);
        a1 = fmaf(bf2f(v1.y), w1, a1);
        a2 = fmaf(bf2f(v1.z), w1, a2);
        a3 = fmaf(bf2f(v1.w), w1, a3);
    }
    if (p < cnt) {
        float4 m0 = rec[p];
        int s0 = __float_as_int(m0.x);
        float w0 = (WSEL == 0) ? m0.y : (WSEL == 1) ? m0.z : m0.w;
        ushort4 v0 = yv[(size_t)s0 * TPN + lane];
        a0 = fmaf(bf2f(v0.x), w0, a0);
        a1 = fmaf(bf2f(v0.y), w0, a1);
        a2 = fmaf(bf2f(v0.z), w0, a2);
        a3 = fmaf(bf2f(v0.w), w0, a3);
    }
    if (dg > CAP) {                      // rare exact-overflow path
        int sc = *spill_cnt;
        for (int i = 0; i < sc; ++i) {
            int2 sp = spill[i];
            if (sp.x == n) {
                int e = sp.y;
                int s0 = src[e];
                float w0 = wl[e];
                ushort4 v0 = yv[(size_t)s0 * TPN + lane];
                a0 = fmaf(bf2f(v0.x), w0, a0);
                a1 = fmaf(bf2f(v0.y), w0, a1);
                a2 = fmaf(bf2f(v0.z), w0, a2);
                a3 = fmaf(bf2f(v0.w), w0, a3);
            }
        }
    }

    const float inv = invi[n];
    if (FINAL) {
        float* out = (float*)outp;
        const int c = lane * 4;
        float acc[4] = {a0, a1, a2, a3};
        #pragma unroll
        for (int j = 0; j < 4; ++j) {
            if (c + j < 47) out[(size_t)n * 47 + c + j] = fmaf(acc[j], inv, b[c + j]);
        }
    } else {
        unsigned short* out = (unsigned short*)outp;
        const float io = invo[n];
        float4 bb = *(const float4*)&b[lane * 4];
        float4 v;
        v.x = fmaxf(fmaf(a0, inv, bb.x), 0.f) * io;
        v.y = fmaxf(fmaf(a1, inv, bb.y), 0.f) * io;
        v.z = fmaxf(fmaf(a2, inv, bb.z), 0.f) * io;
        v.w = fmaxf(fmaf(a3, inv, bb.w), 0.f) * io;
        ushort4 o;
        o.x = f2bf(v.x); o.y = f2bf(v.y); o.z = f2bf(v.z); o.w = f2bf(v.w);
        *(ushort4*)&out[(size_t)n * D + lane * 4] = o;
    }
}

extern "C" void kernel_launch(void* const* d_in, const int* in_sizes, int n_in,
                              void* d_out, int out_size, void* d_ws, size_t ws_size,
                              hipStream_t stream) {
    const float* x   = (const float*)d_in[0];
    const int*   src = (const int*)d_in[1];
    const int*   dst = (const int*)d_in[2];
    const float* w   = (const float*)d_in[3];
    const float* W0  = (const float*)d_in[4];
    const float* b0  = (const float*)d_in[5];
    const float* W1  = (const float*)d_in[6];
    const float* b1  = (const float*)d_in[7];
    const float* W2  = (const float*)d_in[8];
    const float* b2  = (const float*)d_in[9];

    const int N = in_sizes[0] / 128;
    const int E = in_sizes[1];

    char* p = (char*)d_ws;
    unsigned short* xb = (unsigned short*)p; p += (size_t)N * 128 * sizeof(unsigned short);
    unsigned short* hb = (unsigned short*)p; p += (size_t)N * 128 * sizeof(unsigned short);
    unsigned short* y  = (unsigned short*)p; p += (size_t)N * 128 * sizeof(unsigned short);
    float4* swb    = (float4*)p; p += (size_t)N * CAP * sizeof(float4);
    int2*   spill  = (int2*)p;   p += (size_t)E * sizeof(int2);
    unsigned short* Wp = (unsigned short*)p; p += (size_t)(4 * 8 * 64 * 8 * 2 + 4 * 4 * 64 * 8) * sizeof(unsigned short);
    int*   dego    = (int*)p;    p += (size_t)N * sizeof(int);
    int*   cursor  = (int*)p;    p += (size_t)N * sizeof(int);   // becomes degi
    int*   spill_cnt = (int*)p;  p += 4 * sizeof(int);
    float* invo    = (float*)p;  p += (size_t)N * sizeof(float);
    float* invi    = (float*)p;  p += (size_t)N * sizeof(float);

    unsigned short* Wp0 = Wp;                    // 4*8*64*8 = 16384 elems
    unsigned short* Wp1 = Wp + 16384;
    unsigned short* Wp2 = Wp + 32768;            // 4*4*64*8 = 8192 elems

    // ---- weight packs (independent) ----
    pack_w<<<(128 * 128 + 255) / 256, 256, 0, stream>>>(W0, 128, 128, Wp0);
    pack_w<<<(128 * 128 + 255) / 256, 256, 0, stream>>>(W1, 128, 128, Wp1);
    pack_w<<<(128 * 64 + 255) / 256, 256, 0, stream>>>(W2, 47, 64, Wp2);

    // ---- fused bucket build (degrees + records + spill) ----
    hipMemsetAsync(dego, 0, (2 * (size_t)N + 4) * sizeof(int), stream);
    fill_bucket<<<(E + 255) / 256, 256, 0, stream>>>(
        src, dst, w, E, dego, cursor, swb, spill_cnt, spill);
    invsqrt_kernel<<<(N + 255) / 256, 256, 0, stream>>>(dego, cursor, invo, invi, N);

    // ---- layer-0 input prescale ----
    prescale<<<(N * 32 + 255) / 256, 256, 0, stream>>>(x, invo, xb, N);

    const int gemm_blocks = (N + 63) / 64;

    // ---- layer 0: xb -> hb ----
    gemm_direct<128><<<gemm_blocks, 256, 0, stream>>>(xb, Wp0, y, N);
    gather_b<128, 0, false><<<(N + 7) / 8, 256, 0, stream>>>(
        y, swb, cursor, spill_cnt, spill, src, w, invi, invo, b0, hb, N);

    // ---- layer 1: hb -> hb ----
    gemm_direct<128><<<gemm_blocks, 256, 0, stream>>>(hb, Wp1, y, N);
    gather_b<128, 1, false><<<(N + 7) / 8, 256, 0, stream>>>(
        y, swb, cursor, spill_cnt, spill, src, w + E, invi, invo, b1, hb, N);

    // ---- layer 2: hb -> d_out ----
    gemm_direct<64><<<gemm_blocks, 256, 0, stream>>>(hb, Wp2, y, N);
    gather_b<64, 2, true><<<(N + 15) / 16, 256, 0, stream>>>(
        y, swb, cursor, spill_cnt, spill, src, w + 2 * (size_t)E, invi, invo, b2, d_out, N);
}